// Round 7
// baseline (164.640 us; speedup 1.0000x reference)
//
#include <hip/hip_runtime.h>
#include <hip/hip_bf16.h>

// x: (B=4, T=5, C=3, H=128, W=128) fp32 ; R=2 ; D = 60 ; N = 4096
#define BB 4
#define TC 15
#define DD 60
#define NN 4096
#define HH 128
#define DP 64
#define KT 64
#define NWAVE 8
#define QT 128
#define NTILES 64
#define NSPLIT 8
#define L2E 1.4426950408889634f

typedef short s8v __attribute__((ext_vector_type(8)));   // 8 x bf16
typedef ushort u4v __attribute__((ext_vector_type(4)));
typedef float f4v __attribute__((ext_vector_type(4)));
typedef float f2v __attribute__((ext_vector_type(2)));

static __device__ __forceinline__ ushort f2bf_bits(float f) {
    __hip_bfloat16 h = __float2bfloat16(f);
    return *reinterpret_cast<ushort*>(&h);
}
static __device__ __forceinline__ float bf2f_lo(uint u) { return __uint_as_float(u << 16); }
static __device__ __forceinline__ float bf2f_hi(uint u) { return __uint_as_float(u & 0xFFFF0000u); }

// ---------- K1: pixel-unshuffle -> xf_bf (B,D,N) bf16, vec2 along n ----------
__global__ __launch_bounds__(256) void k_unshuf_bf(const float* __restrict__ x,
                                                   ushort* __restrict__ xf_bf,
                                                   uint* __restrict__ mxbits) {
    if (blockIdx.x == 0 && threadIdx.x < BB) mxbits[threadIdx.x] = 0;
    int u = blockIdx.x * 256 + threadIdx.x;            // over elems/2
    int idx = u * 2;
    int n = idx & (NN - 1);
    int d = (idx >> 12) % DD;
    int b = idx / (DD * NN);
    int oh = n >> 6, ow = n & 63;
    int c1 = d >> 2, r1 = (d >> 1) & 1, r2 = d & 1;
    const float* xs = x + ((b * TC + c1) * HH + oh * 2 + r1) * HH + ow * 2 + r2;
    uint pack = (uint)f2bf_bits(xs[0]) | ((uint)f2bf_bits(xs[2]) << 16);
    *(uint*)&xf_bf[idx] = pack;
}

// ---------- K1b: transpose -> xf_t (B,N,64) bf16 (padded); row norms + batch max norm ----------
__global__ __launch_bounds__(256) void k_transpose(const ushort* __restrict__ xf_bf,
                                                   ushort* __restrict__ xf_t,
                                                   float* __restrict__ rnorm,
                                                   uint* __restrict__ mxbits) {
    int e = blockIdx.x * 256 + threadIdx.x;            // over B*N*8 = 131072
    int j = e & 7;
    int ng = e >> 3;                                   // b*N + n
    int b = ng >> 12, n = ng & (NN - 1);
    const ushort* src = xf_bf + b * DD * NN + n;
    ushort v[8];
    float ss = 0.f;
    #pragma unroll
    for (int jj = 0; jj < 8; ++jj) {
        int d = j * 8 + jj;
        ushort w = (d < DD) ? src[d * NN] : (ushort)0;
        v[jj] = w;
        float f = __uint_as_float((uint)w << 16);
        ss += f * f;
    }
    *(s8v*)&xf_t[(size_t)ng * DP + j * 8] = *(s8v*)v;
    #pragma unroll
    for (int off = 1; off < 8; off <<= 1) ss += __shfl_xor(ss, off);
    float norm = sqrtf(ss) * 1.0002f;                  // safety margin: m must bound row max
    if (j == 0) rnorm[ng] = norm;
    float mv = (j == 0) ? norm : 0.f;
    #pragma unroll
    for (int off = 8; off < 64; off <<= 1) mv = fmaxf(mv, __shfl_xor(mv, off));
    if ((threadIdx.x & 63) == 0) atomicMax(&mxbits[b], __float_as_uint(mv));
}

// ---------- K2: G (B,D,N) bf16 = g_w . xf + g_b, vec2 along n ----------
__global__ __launch_bounds__(256) void k_gproj(const ushort* __restrict__ xf_bf,
                                               const float* __restrict__ g_w,
                                               const float* __restrict__ g_b,
                                               ushort* __restrict__ G_bf) {
    int u = blockIdx.x * 256 + threadIdx.x;            // over elems/2
    int idx = u * 2;
    int n = idx & (NN - 1);
    int o = (idx >> 12) % DD;                          // block-uniform
    int b = idx / (DD * NN);
    const ushort* X = xf_bf + b * DD * NN;
    float a0 = g_b[o], a1 = a0;
    #pragma unroll
    for (int d = 0; d < DD; ++d) {
        uint w = *(const uint*)&X[d * NN + n];
        float gw = g_w[o * DD + d];
        a0 += gw * bf2f_lo(w);
        a1 += gw * bf2f_hi(w);
    }
    uint pack = (uint)f2bf_bits(a0) | ((uint)f2bf_bits(a1) << 16);
    *(uint*)&G_bf[idx] = pack;
}

// ---------- K3: flash attention, bf16 MFMA, fixed per-row softmax shift, split-K ----------
// m_n = rnorm[n]*mxnorm[b] >= row max (Cauchy-Schwarz) -> no max tracking, no rescale.
// l folded into PV via G row 60 == 1.0. 8 waves/block, QT=128 query rows.
template <int NS>
__global__ __launch_bounds__(512, 8) void k_attn(const ushort* __restrict__ xf_t,
                                                 const ushort* __restrict__ G_bf,
                                                 const float* __restrict__ rnorm,
                                                 const uint* __restrict__ mxbits,
                                                 float* __restrict__ Y,        // NS==1
                                                 ushort* __restrict__ O_bf) {  // NS>1: (s,b,64,N) bf16
    __shared__ char K_lds[KT * 128];
    __shared__ char G_lds[DP * 128];
    __shared__ char P_lds[NWAVE][16 * 128];

    int p = blockIdx.x;
    int s, b, q0;
    if (NS == NSPLIT) {
        // XCD-aware: xcd = p&7; each XCD pair-half owns one batch (4MB = one L2)
        int xcd = p & 7, slot = p >> 3;                // slot in [0,128)
        b = xcd >> 1;
        s = (xcd & 1) * 4 + (slot >> 5);
        q0 = (slot & 31) * QT;
    } else {
        s = 0;
        b = p >> 5;
        q0 = (p & 31) * QT;
    }
    int tid = threadIdx.x;
    int lane = tid & 63, wv = tid >> 6;
    int r = lane & 15, g = lane >> 4;

    const ushort* Xt = xf_t + (size_t)b * NN * DP;
    const ushort* Gb = G_bf + (size_t)b * DD * NN;

    int qrow = q0 + wv * 16 + r;
    s8v qa[2];
    qa[0] = *(const s8v*)&Xt[(size_t)qrow * DP + g * 8];
    qa[1] = *(const s8v*)&Xt[(size_t)qrow * DP + 32 + g * 8];

    // fixed per-row shift, rows 4g+0..3 of this lane
    float mx = __uint_as_float(mxbits[b]);
    float nm[4];
    #pragma unroll
    for (int reg = 0; reg < 4; ++reg)
        nm[reg] = -rnorm[b * NN + q0 + wv * 16 + 4 * g + reg] * mx * L2E;

    f4v of[4];
    #pragma unroll
    for (int i = 0; i < 4; ++i) of[i] = (f4v){0.f, 0.f, 0.f, 0.f};

    // staging: 512 threads x one 16B unit each per buffer; row = tid>>3, j = tid&7
    const int kr0 = tid >> 3, kj0 = tid & 7;
    const int kw0 = (kr0 * 128 + kj0 * 16) ^ ((kr0 & 7) << 4);
    const s8v ones8 = {(short)0x3F80, (short)0x3F80, (short)0x3F80, (short)0x3F80,
                       (short)0x3F80, (short)0x3F80, (short)0x3F80, (short)0x3F80};
    const s8v zero8 = {0, 0, 0, 0, 0, 0, 0, 0};
    s8v kp0, gp0;

    auto stage_regs = [&](int t) {
        int n0 = t * KT;
        kp0 = *(const s8v*)&Xt[(size_t)(n0 + kr0) * DP + kj0 * 8];
        gp0 = (kr0 < DD) ? *(const s8v*)&Gb[(size_t)kr0 * NN + n0 + kj0 * 8]
                         : (kr0 == DD ? ones8 : zero8);
    };
    auto lds_write = [&]() {
        *(s8v*)(K_lds + kw0) = kp0;
        *(s8v*)(G_lds + kw0) = gp0;
    };

    const int t0 = s * (NTILES / NS);
    const int tend = t0 + NTILES / NS;
    char* Pw = P_lds[wv];

    stage_regs(t0);
    lds_write();
    __syncthreads();

    #pragma unroll 1
    for (int t = t0; t < tend; ++t) {
        bool more = (t + 1 < tend);
        if (more) stage_regs(t + 1);          // global loads in flight during compute

        // ---- S = Q.K^T ----
        f4v sf[4];
        #pragma unroll
        for (int i = 0; i < 4; ++i) sf[i] = (f4v){0.f, 0.f, 0.f, 0.f};
        __builtin_amdgcn_s_setprio(1);
        #pragma unroll
        for (int kt2 = 0; kt2 < 4; ++kt2)
            #pragma unroll
            for (int kb = 0; kb < 2; ++kb) {
                int off = (((kt2 * 16 + r) * 128) + kb * 64 + g * 16) ^ ((r & 7) << 4);
                s8v bf = *(const s8v*)(K_lds + off);
                sf[kt2] = __builtin_amdgcn_mfma_f32_16x16x32_bf16(qa[kb], bf, sf[kt2], 0, 0, 0);
            }
        __builtin_amdgcn_s_setprio(0);

        // ---- P = 2^(S*log2e + nm), bf16 into wave-private swizzled LDS ----
        #pragma unroll
        for (int kt2 = 0; kt2 < 4; ++kt2)
            #pragma unroll
            for (int reg = 0; reg < 4; ++reg) {
                float pv = __builtin_exp2f(fmaf(sf[kt2][reg], L2E, nm[reg]));
                int row = 4 * g + reg;
                int boff = ((row * 128) + kt2 * 32 + 2 * r) ^ ((row & 7) << 4);
                *(ushort*)(Pw + boff) = f2bf_bits(pv);
            }

        // ---- O += P . G^T  (col 60 accumulates the denominator l) ----
        __builtin_amdgcn_s_setprio(1);
        #pragma unroll
        for (int kb = 0; kb < 2; ++kb) {
            int poff = ((r * 128) + kb * 64 + g * 16) ^ ((r & 7) << 4);
            s8v pa = *(const s8v*)(Pw + poff);
            #pragma unroll
            for (int ot = 0; ot < 4; ++ot) {
                int goff = (((ot * 16 + r) * 128) + kb * 64 + g * 16) ^ ((r & 7) << 4);
                s8v gf = *(const s8v*)(G_lds + goff);
                of[ot] = __builtin_amdgcn_mfma_f32_16x16x32_bf16(pa, gf, of[ot], 0, 0, 0);
            }
        }
        __builtin_amdgcn_s_setprio(0);

        if (more) {
            __syncthreads();
            lds_write();
            __syncthreads();
        }
    }

    int qb = q0 + wv * 16 + 4 * g;
    if (NS == 1) {
        float linv[4];
        #pragma unroll
        for (int reg = 0; reg < 4; ++reg)
            linv[reg] = 1.0f / __shfl(of[3][reg], 12, 16);   // o=60 column holds l
        #pragma unroll
        for (int ot = 0; ot < 4; ++ot) {
            int o = ot * 16 + r;
            if (o < DD) {
                f4v v;
                #pragma unroll
                for (int reg = 0; reg < 4; ++reg) v[reg] = of[ot][reg] * linv[reg];
                *(f4v*)&Y[((size_t)(b * DD + o)) * NN + qb] = v;
            }
        }
    } else {
        ushort* Ob = O_bf + ((size_t)(s * BB + b) * DP) * NN;
        #pragma unroll
        for (int ot = 0; ot < 4; ++ot) {
            int o = ot * 16 + r;
            u4v v = {f2bf_bits(of[ot][0]), f2bf_bits(of[ot][1]),
                     f2bf_bits(of[ot][2]), f2bf_bits(of[ot][3])};
            *(u4v*)&Ob[(size_t)o * NN + qb] = v;                 // coalesced 32B per r-group
        }
    }
}

// ---------- K3b: combine split partials (shared m -> plain sums) -> Y (B,D,N), vec2 ----------
__global__ __launch_bounds__(256) void k_combine(const ushort* __restrict__ O_bf,
                                                 float* __restrict__ Y) {
    int u = blockIdx.x * 256 + threadIdx.x;            // over elems/2
    int idx = u * 2;
    int n = idx & (NN - 1);
    int o = (idx >> 12) % DD;
    int b = idx / (DD * NN);
    float a0 = 0.f, a1 = 0.f, L0 = 0.f, L1 = 0.f;
    #pragma unroll
    for (int s = 0; s < NSPLIT; ++s) {
        const ushort* Ob = O_bf + ((size_t)(s * BB + b) * DP) * NN + n;
        uint ov = *(const uint*)&Ob[(size_t)o * NN];
        uint lv = *(const uint*)&Ob[(size_t)DD * NN];
        a0 += bf2f_lo(ov); a1 += bf2f_hi(ov);
        L0 += bf2f_lo(lv); L1 += bf2f_hi(lv);
    }
    f2v y = {a0 / L0, a1 / L1};
    *(f2v*)&Y[idx] = y;
}

// ---------- K4: out = pixel_shuffle(w_w.Y + w_b) + x, pixel-major, vec2 over w ----------
__global__ __launch_bounds__(256) void k_out(const float* __restrict__ Y,
                                             const float* __restrict__ w_w,
                                             const float* __restrict__ w_b,
                                             const float* __restrict__ x,
                                             float* __restrict__ out) {
    __shared__ float ww[DD * DD];
    __shared__ float wb[DD];
    for (int i = threadIdx.x; i < DD * DD; i += 256) ww[i] = w_w[i];
    if (threadIdx.x < DD) wb[threadIdx.x] = w_b[threadIdx.x];
    __syncthreads();
    int u = blockIdx.x * 256 + threadIdx.x;            // over B*TC*H*(W/2)
    int w2 = u & 63;
    int h = (u >> 6) & 127;
    int rest = u >> 13;
    int c1 = rest % TC;
    int b = rest / TC;
    int o0 = c1 * 4 + (h & 1) * 2;                     // wave-uniform
    int n = ((h >> 1) << 6) + w2;
    const float* Yb = Y + (size_t)b * DD * NN + n;
    float a0 = wb[o0], a1 = wb[o0 + 1];
    #pragma unroll
    for (int d = 0; d < DD; ++d) {
        float y = Yb[(size_t)d * NN];
        a0 += ww[o0 * DD + d] * y;
        a1 += ww[(o0 + 1) * DD + d] * y;
    }
    size_t xi = ((size_t)(b * TC + c1) * HH + h) * HH + 2 * w2;
    f2v xv = *(const f2v*)&x[xi];
    f2v res = {a0 + xv[0], a1 + xv[1]};
    *(f2v*)&out[xi] = res;
}

extern "C" void kernel_launch(void* const* d_in, const int* in_sizes, int n_in,
                              void* d_out, int out_size, void* d_ws, size_t ws_size,
                              hipStream_t stream) {
    const float* x   = (const float*)d_in[0];
    const float* g_w = (const float*)d_in[1];
    const float* g_b = (const float*)d_in[2];
    const float* w_w = (const float*)d_in[3];
    const float* w_b = (const float*)d_in[4];
    float* out = (float*)d_out;

    char* ws = (char*)d_ws;
    ushort* xf_bf  = (ushort*)ws;                      // 1,966,080 B
    ushort* xf_t   = (ushort*)(ws + 1966080);          // 2,097,152 B
    ushort* G_bf   = (ushort*)(ws + 4063232);          // 1,966,080 B
    float*  rnorm  = (float*)(ws + 6029312);           // 65,536 B
    uint*   mxbits = (uint*)(ws + 6094848);            // 256 B (16 used)
    ushort* O_bf   = (ushort*)(ws + 6095104);          // 16,777,216 B -> end 22,872,320
    const size_t SPLIT_NEED = 22872320;

    k_unshuf_bf<<<1920, 256, 0, stream>>>(x, xf_bf, mxbits);
    k_transpose<<<512, 256, 0, stream>>>(xf_bf, xf_t, rnorm, mxbits);
    k_gproj<<<1920, 256, 0, stream>>>(xf_bf, g_w, g_b, G_bf);

    float* Y;
    if (ws_size >= SPLIT_NEED) {
        k_attn<NSPLIT><<<NSPLIT * BB * (NN / QT), 512, 0, stream>>>(
            xf_t, G_bf, rnorm, mxbits, nullptr, O_bf);
        Y = (float*)ws;                                // alias xf_bf+xf_t (dead after attn)
        k_combine<<<1920, 256, 0, stream>>>(O_bf, Y);
    } else {
        Y = (float*)(ws + 6095104);
        k_attn<1><<<BB * (NN / QT), 512, 0, stream>>>(
            xf_t, G_bf, rnorm, mxbits, Y, nullptr);
    }
    k_out<<<1920, 256, 0, stream>>>(Y, w_w, w_b, x, out);
}

// Round 8
// 100.809 us; speedup vs baseline: 1.6332x; 1.6332x over previous
//
#include <hip/hip_runtime.h>
#include <hip/hip_bf16.h>

// x: (B=4, T=5, C=3, H=128, W=128) fp32 ; R=2 ; D = 60 ; N = 4096
#define BB 4
#define TC 15
#define DD 60
#define NN 4096
#define HH 128
#define DP 64
#define KT 64
#define NWAVE 8
#define QT 128
#define NTILES 64
#define NSPLIT 8
#define L2E 1.4426950408889634f

typedef short s8v __attribute__((ext_vector_type(8)));   // 8 x bf16
typedef ushort u4v __attribute__((ext_vector_type(4)));
typedef float f4v __attribute__((ext_vector_type(4)));
typedef float f2v __attribute__((ext_vector_type(2)));

static __device__ __forceinline__ ushort f2bf_bits(float f) {
    __hip_bfloat16 h = __float2bfloat16(f);
    return *reinterpret_cast<ushort*>(&h);
}
static __device__ __forceinline__ float bf2f_lo(uint u) { return __uint_as_float(u << 16); }
static __device__ __forceinline__ float bf2f_hi(uint u) { return __uint_as_float(u & 0xFFFF0000u); }

// ---------- K1: pixel-unshuffle -> xf_bf (B,D,N) bf16, vec2 along n ----------
__global__ __launch_bounds__(256) void k_unshuf_bf(const float* __restrict__ x,
                                                   ushort* __restrict__ xf_bf,
                                                   uint* __restrict__ mxbits) {
    if (blockIdx.x == 0 && threadIdx.x < BB) mxbits[threadIdx.x] = 0;
    int u = blockIdx.x * 256 + threadIdx.x;            // over elems/2
    int idx = u * 2;
    int n = idx & (NN - 1);
    int d = (idx >> 12) % DD;
    int b = idx / (DD * NN);
    int oh = n >> 6, ow = n & 63;
    int c1 = d >> 2, r1 = (d >> 1) & 1, r2 = d & 1;
    const float* xs = x + ((b * TC + c1) * HH + oh * 2 + r1) * HH + ow * 2 + r2;
    uint pack = (uint)f2bf_bits(xs[0]) | ((uint)f2bf_bits(xs[2]) << 16);
    *(uint*)&xf_bf[idx] = pack;
}

// ---------- K1b: transpose -> xf_t (B,N,64) bf16 (padded); row norms + batch max norm ----------
__global__ __launch_bounds__(256) void k_transpose(const ushort* __restrict__ xf_bf,
                                                   ushort* __restrict__ xf_t,
                                                   float* __restrict__ rnorm,
                                                   uint* __restrict__ mxbits) {
    int e = blockIdx.x * 256 + threadIdx.x;            // over B*N*8 = 131072
    int j = e & 7;
    int ng = e >> 3;                                   // b*N + n
    int b = ng >> 12, n = ng & (NN - 1);
    const ushort* src = xf_bf + b * DD * NN + n;
    ushort v[8];
    float ss = 0.f;
    #pragma unroll
    for (int jj = 0; jj < 8; ++jj) {
        int d = j * 8 + jj;
        ushort w = (d < DD) ? src[d * NN] : (ushort)0;
        v[jj] = w;
        float f = __uint_as_float((uint)w << 16);
        ss += f * f;
    }
    *(s8v*)&xf_t[(size_t)ng * DP + j * 8] = *(s8v*)v;
    #pragma unroll
    for (int off = 1; off < 8; off <<= 1) ss += __shfl_xor(ss, off);
    float norm = sqrtf(ss) * 1.0002f;                  // safety margin: m must bound row max
    if (j == 0) rnorm[ng] = norm;
    float mv = (j == 0) ? norm : 0.f;
    #pragma unroll
    for (int off = 8; off < 64; off <<= 1) mv = fmaxf(mv, __shfl_xor(mv, off));
    if ((threadIdx.x & 63) == 0) atomicMax(&mxbits[b], __float_as_uint(mv));
}

// ---------- K2: G (B,D,N) bf16 = g_w . xf + g_b, vec2 along n ----------
__global__ __launch_bounds__(256) void k_gproj(const ushort* __restrict__ xf_bf,
                                               const float* __restrict__ g_w,
                                               const float* __restrict__ g_b,
                                               ushort* __restrict__ G_bf) {
    int u = blockIdx.x * 256 + threadIdx.x;            // over elems/2
    int idx = u * 2;
    int n = idx & (NN - 1);
    int o = (idx >> 12) % DD;                          // block-uniform
    int b = idx / (DD * NN);
    const ushort* X = xf_bf + b * DD * NN;
    float a0 = g_b[o], a1 = a0;
    #pragma unroll
    for (int d = 0; d < DD; ++d) {
        uint w = *(const uint*)&X[d * NN + n];
        float gw = g_w[o * DD + d];
        a0 += gw * bf2f_lo(w);
        a1 += gw * bf2f_hi(w);
    }
    uint pack = (uint)f2bf_bits(a0) | ((uint)f2bf_bits(a1) << 16);
    *(uint*)&G_bf[idx] = pack;
}

// ---------- K3: flash attention, bf16 MFMA, fixed per-row softmax shift, split-K ----------
// m_n = rnorm[n]*mxnorm[b] >= row max (Cauchy-Schwarz) -> no max tracking, no rescale.
// l folded into PV via G row 60 == 1.0. 8 waves/block, QT=128 query rows.
// __launch_bounds__(512,4): 128-VGPR budget. (512,8) forced 64 -> massive scratch
// spills (428 MB HBM traffic/dispatch, round 7). 4 waves/SIMD is the no-spill max.
template <int NS>
__global__ __launch_bounds__(512, 4) void k_attn(const ushort* __restrict__ xf_t,
                                                 const ushort* __restrict__ G_bf,
                                                 const float* __restrict__ rnorm,
                                                 const uint* __restrict__ mxbits,
                                                 float* __restrict__ Y,        // NS==1
                                                 ushort* __restrict__ O_bf) {  // NS>1: (s,b,64,N) bf16
    __shared__ char K_lds[KT * 128];
    __shared__ char G_lds[DP * 128];
    __shared__ char P_lds[NWAVE][16 * 128];

    int p = blockIdx.x;
    int s, b, q0;
    if (NS == NSPLIT) {
        // XCD-aware: xcd = p&7; each XCD pair-half owns one batch (4MB = one L2)
        int xcd = p & 7, slot = p >> 3;                // slot in [0,128)
        b = xcd >> 1;
        s = (xcd & 1) * 4 + (slot >> 5);
        q0 = (slot & 31) * QT;
    } else {
        s = 0;
        b = p >> 5;
        q0 = (p & 31) * QT;
    }
    int tid = threadIdx.x;
    int lane = tid & 63, wv = tid >> 6;
    int r = lane & 15, g = lane >> 4;

    const ushort* Xt = xf_t + (size_t)b * NN * DP;
    const ushort* Gb = G_bf + (size_t)b * DD * NN;

    int qrow = q0 + wv * 16 + r;
    s8v qa[2];
    qa[0] = *(const s8v*)&Xt[(size_t)qrow * DP + g * 8];
    qa[1] = *(const s8v*)&Xt[(size_t)qrow * DP + 32 + g * 8];

    // fixed per-row shift, rows 4g+0..3 of this lane
    float mx = __uint_as_float(mxbits[b]);
    float nm[4];
    #pragma unroll
    for (int reg = 0; reg < 4; ++reg)
        nm[reg] = -rnorm[b * NN + q0 + wv * 16 + 4 * g + reg] * mx * L2E;

    f4v of[4];
    #pragma unroll
    for (int i = 0; i < 4; ++i) of[i] = (f4v){0.f, 0.f, 0.f, 0.f};

    // staging: 512 threads x one 16B unit each per buffer; row = tid>>3, j = tid&7
    const int kr0 = tid >> 3, kj0 = tid & 7;
    const int kw0 = (kr0 * 128 + kj0 * 16) ^ ((kr0 & 7) << 4);
    const s8v ones8 = {(short)0x3F80, (short)0x3F80, (short)0x3F80, (short)0x3F80,
                       (short)0x3F80, (short)0x3F80, (short)0x3F80, (short)0x3F80};
    const s8v zero8 = {0, 0, 0, 0, 0, 0, 0, 0};
    s8v kp0, gp0;

    auto stage_regs = [&](int t) {
        int n0 = t * KT;
        kp0 = *(const s8v*)&Xt[(size_t)(n0 + kr0) * DP + kj0 * 8];
        gp0 = (kr0 < DD) ? *(const s8v*)&Gb[(size_t)kr0 * NN + n0 + kj0 * 8]
                         : (kr0 == DD ? ones8 : zero8);
    };
    auto lds_write = [&]() {
        *(s8v*)(K_lds + kw0) = kp0;
        *(s8v*)(G_lds + kw0) = gp0;
    };

    const int t0 = s * (NTILES / NS);
    const int tend = t0 + NTILES / NS;
    char* Pw = P_lds[wv];

    stage_regs(t0);
    lds_write();
    __syncthreads();

    #pragma unroll 1
    for (int t = t0; t < tend; ++t) {
        bool more = (t + 1 < tend);
        if (more) stage_regs(t + 1);          // global loads in flight during compute

        // ---- S = Q.K^T ----
        f4v sf[4];
        #pragma unroll
        for (int i = 0; i < 4; ++i) sf[i] = (f4v){0.f, 0.f, 0.f, 0.f};
        __builtin_amdgcn_s_setprio(1);
        #pragma unroll
        for (int kt2 = 0; kt2 < 4; ++kt2)
            #pragma unroll
            for (int kb = 0; kb < 2; ++kb) {
                int off = (((kt2 * 16 + r) * 128) + kb * 64 + g * 16) ^ ((r & 7) << 4);
                s8v bf = *(const s8v*)(K_lds + off);
                sf[kt2] = __builtin_amdgcn_mfma_f32_16x16x32_bf16(qa[kb], bf, sf[kt2], 0, 0, 0);
            }
        __builtin_amdgcn_s_setprio(0);

        // ---- P = 2^(S*log2e + nm), bf16 into wave-private swizzled LDS ----
        #pragma unroll
        for (int kt2 = 0; kt2 < 4; ++kt2)
            #pragma unroll
            for (int reg = 0; reg < 4; ++reg) {
                float pv = __builtin_exp2f(fmaf(sf[kt2][reg], L2E, nm[reg]));
                int row = 4 * g + reg;
                int boff = ((row * 128) + kt2 * 32 + 2 * r) ^ ((row & 7) << 4);
                *(ushort*)(Pw + boff) = f2bf_bits(pv);
            }

        // ---- O += P . G^T  (col 60 accumulates the denominator l) ----
        __builtin_amdgcn_s_setprio(1);
        #pragma unroll
        for (int kb = 0; kb < 2; ++kb) {
            int poff = ((r * 128) + kb * 64 + g * 16) ^ ((r & 7) << 4);
            s8v pa = *(const s8v*)(Pw + poff);
            #pragma unroll
            for (int ot = 0; ot < 4; ++ot) {
                int goff = (((ot * 16 + r) * 128) + kb * 64 + g * 16) ^ ((r & 7) << 4);
                s8v gf = *(const s8v*)(G_lds + goff);
                of[ot] = __builtin_amdgcn_mfma_f32_16x16x32_bf16(pa, gf, of[ot], 0, 0, 0);
            }
        }
        __builtin_amdgcn_s_setprio(0);

        if (more) {
            __syncthreads();
            lds_write();
            __syncthreads();
        }
    }

    int qb = q0 + wv * 16 + 4 * g;
    if (NS == 1) {
        float linv[4];
        #pragma unroll
        for (int reg = 0; reg < 4; ++reg)
            linv[reg] = 1.0f / __shfl(of[3][reg], 12, 16);   // o=60 column holds l
        #pragma unroll
        for (int ot = 0; ot < 4; ++ot) {
            int o = ot * 16 + r;
            if (o < DD) {
                f4v v;
                #pragma unroll
                for (int reg = 0; reg < 4; ++reg) v[reg] = of[ot][reg] * linv[reg];
                *(f4v*)&Y[((size_t)(b * DD + o)) * NN + qb] = v;
            }
        }
    } else {
        ushort* Ob = O_bf + ((size_t)(s * BB + b) * DP) * NN;
        #pragma unroll
        for (int ot = 0; ot < 4; ++ot) {
            int o = ot * 16 + r;
            u4v v = {f2bf_bits(of[ot][0]), f2bf_bits(of[ot][1]),
                     f2bf_bits(of[ot][2]), f2bf_bits(of[ot][3])};
            *(u4v*)&Ob[(size_t)o * NN + qb] = v;                 // coalesced 32B per r-group
        }
    }
}

// ---------- K3b: combine split partials (shared m -> plain sums) -> Y (B,D,N), vec2 ----------
__global__ __launch_bounds__(256) void k_combine(const ushort* __restrict__ O_bf,
                                                 float* __restrict__ Y) {
    int u = blockIdx.x * 256 + threadIdx.x;            // over elems/2
    int idx = u * 2;
    int n = idx & (NN - 1);
    int o = (idx >> 12) % DD;
    int b = idx / (DD * NN);
    float a0 = 0.f, a1 = 0.f, L0 = 0.f, L1 = 0.f;
    #pragma unroll
    for (int s = 0; s < NSPLIT; ++s) {
        const ushort* Ob = O_bf + ((size_t)(s * BB + b) * DP) * NN + n;
        uint ov = *(const uint*)&Ob[(size_t)o * NN];
        uint lv = *(const uint*)&Ob[(size_t)DD * NN];
        a0 += bf2f_lo(ov); a1 += bf2f_hi(ov);
        L0 += bf2f_lo(lv); L1 += bf2f_hi(lv);
    }
    f2v y = {a0 / L0, a1 / L1};
    *(f2v*)&Y[idx] = y;
}

// ---------- K4: out = pixel_shuffle(w_w.Y + w_b) + x, pixel-major, vec2 over w ----------
__global__ __launch_bounds__(256) void k_out(const float* __restrict__ Y,
                                             const float* __restrict__ w_w,
                                             const float* __restrict__ w_b,
                                             const float* __restrict__ x,
                                             float* __restrict__ out) {
    __shared__ float ww[DD * DD];
    __shared__ float wb[DD];
    for (int i = threadIdx.x; i < DD * DD; i += 256) ww[i] = w_w[i];
    if (threadIdx.x < DD) wb[threadIdx.x] = w_b[threadIdx.x];
    __syncthreads();
    int u = blockIdx.x * 256 + threadIdx.x;            // over B*TC*H*(W/2)
    int w2 = u & 63;
    int h = (u >> 6) & 127;
    int rest = u >> 13;
    int c1 = rest % TC;
    int b = rest / TC;
    int o0 = c1 * 4 + (h & 1) * 2;                     // wave-uniform
    int n = ((h >> 1) << 6) + w2;
    const float* Yb = Y + (size_t)b * DD * NN + n;
    float a0 = wb[o0], a1 = wb[o0 + 1];
    #pragma unroll
    for (int d = 0; d < DD; ++d) {
        float y = Yb[(size_t)d * NN];
        a0 += ww[o0 * DD + d] * y;
        a1 += ww[(o0 + 1) * DD + d] * y;
    }
    size_t xi = ((size_t)(b * TC + c1) * HH + h) * HH + 2 * w2;
    f2v xv = *(const f2v*)&x[xi];
    f2v res = {a0 + xv[0], a1 + xv[1]};
    *(f2v*)&out[xi] = res;
}

extern "C" void kernel_launch(void* const* d_in, const int* in_sizes, int n_in,
                              void* d_out, int out_size, void* d_ws, size_t ws_size,
                              hipStream_t stream) {
    const float* x   = (const float*)d_in[0];
    const float* g_w = (const float*)d_in[1];
    const float* g_b = (const float*)d_in[2];
    const float* w_w = (const float*)d_in[3];
    const float* w_b = (const float*)d_in[4];
    float* out = (float*)d_out;

    char* ws = (char*)d_ws;
    ushort* xf_bf  = (ushort*)ws;                      // 1,966,080 B
    ushort* xf_t   = (ushort*)(ws + 1966080);          // 2,097,152 B
    ushort* G_bf   = (ushort*)(ws + 4063232);          // 1,966,080 B
    float*  rnorm  = (float*)(ws + 6029312);           // 65,536 B
    uint*   mxbits = (uint*)(ws + 6094848);            // 256 B (16 used)
    ushort* O_bf   = (ushort*)(ws + 6095104);          // 16,777,216 B -> end 22,872,320
    const size_t SPLIT_NEED = 22872320;

    k_unshuf_bf<<<1920, 256, 0, stream>>>(x, xf_bf, mxbits);
    k_transpose<<<512, 256, 0, stream>>>(xf_bf, xf_t, rnorm, mxbits);
    k_gproj<<<1920, 256, 0, stream>>>(xf_bf, g_w, g_b, G_bf);

    float* Y;
    if (ws_size >= SPLIT_NEED) {
        k_attn<NSPLIT><<<NSPLIT * BB * (NN / QT), 512, 0, stream>>>(
            xf_t, G_bf, rnorm, mxbits, nullptr, O_bf);
        Y = (float*)ws;                                // alias xf_bf+xf_t (dead after attn)
        k_combine<<<1920, 256, 0, stream>>>(O_bf, Y);
    } else {
        Y = (float*)(ws + 6095104);
        k_attn<1><<<BB * (NN / QT), 512, 0, stream>>>(
            xf_t, G_bf, rnorm, mxbits, Y, nullptr);
    }
    k_out<<<1920, 256, 0, stream>>>(Y, w_w, w_b, x, out);
}

// Round 11
// 81.927 us; speedup vs baseline: 2.0096x; 1.2305x over previous
//
#include <hip/hip_runtime.h>
#include <hip/hip_bf16.h>

// x: (B=4, T=5, C=3, H=128, W=128) fp32 ; R=2 ; D = 60 ; N = 4096
#define BB 4
#define TC 15
#define DD 60
#define NN 4096
#define HH 128
#define DP 64
#define KT 64
#define NWAVE 8
#define QT 128
#define NTILES 64
#define NSPLIT 8
#define L2E 1.4426950408889634f

typedef short s8v __attribute__((ext_vector_type(8)));   // 8 x bf16
typedef ushort u4v __attribute__((ext_vector_type(4)));
typedef float f4v __attribute__((ext_vector_type(4)));
typedef float f2v __attribute__((ext_vector_type(2)));

static __device__ __forceinline__ ushort f2bf_bits(float f) {
    __hip_bfloat16 h = __float2bfloat16(f);
    return *reinterpret_cast<ushort*>(&h);
}
static __device__ __forceinline__ float bf2f_lo(uint u) { return __uint_as_float(u << 16); }
static __device__ __forceinline__ float bf2f_hi(uint u) { return __uint_as_float(u & 0xFFFF0000u); }

// ---------- K1 (fused): x -> xf_bf (B,D,N) + xf_t (B,N,64) + rnorm + per-batch max norm ----------
// One thread per pixel (b,n): reads its 60 x-values, writes the coalesced (D,N) copy,
// its own (N,64) row, and its row norm (no shuffles needed). mxbits pre-zeroed by memset.
__global__ __launch_bounds__(64) void k_prep(const float* __restrict__ x,
                                             ushort* __restrict__ xf_bf,
                                             ushort* __restrict__ xf_t,
                                             float* __restrict__ rnorm,
                                             uint* __restrict__ mxbits) {
    int ng = blockIdx.x * 64 + threadIdx.x;            // b*N + n   (block stays within one b)
    int b = ng >> 12, n = ng & (NN - 1);
    int oh = n >> 6, ow = n & 63;
    const float* xb = x + (size_t)b * TC * HH * HH;
    ushort* xbf = xf_bf + (size_t)b * DD * NN + n;
    ushort row[DP];
    float ss = 0.f;
    #pragma unroll
    for (int d = 0; d < DD; ++d) {
        int c1 = d >> 2, r1 = (d >> 1) & 1, r2 = d & 1;
        float v = xb[(c1 * HH + oh * 2 + r1) * HH + ow * 2 + r2];
        ushort w = f2bf_bits(v);
        row[d] = w;
        float f = __uint_as_float((uint)w << 16);
        ss = fmaf(f, f, ss);
        xbf[(size_t)d * NN] = w;                       // coalesced across lanes
    }
    #pragma unroll
    for (int d = DD; d < DP; ++d) row[d] = 0;
    ushort* dst = xf_t + (size_t)ng * DP;
    #pragma unroll
    for (int j = 0; j < 8; ++j)
        *(s8v*)&dst[j * 8] = *(const s8v*)&row[j * 8];
    float norm = sqrtf(ss) * 1.0002f;                  // safety margin: m must bound row max
    rnorm[ng] = norm;
    float mv = norm;
    #pragma unroll
    for (int off = 1; off < 64; off <<= 1) mv = fmaxf(mv, __shfl_xor(mv, off));
    if (threadIdx.x == 0) atomicMax(&mxbits[b], __float_as_uint(mv));
}

// ---------- K2: G (B,D,N) bf16 = g_w . xf + g_b, vec2 along n ----------
__global__ __launch_bounds__(256) void k_gproj(const ushort* __restrict__ xf_bf,
                                               const float* __restrict__ g_w,
                                               const float* __restrict__ g_b,
                                               ushort* __restrict__ G_bf) {
    int u = blockIdx.x * 256 + threadIdx.x;            // over elems/2
    int idx = u * 2;
    int n = idx & (NN - 1);
    int o = (idx >> 12) % DD;                          // block-uniform
    int b = idx / (DD * NN);
    const ushort* X = xf_bf + b * DD * NN;
    float a0 = g_b[o], a1 = a0;
    #pragma unroll
    for (int d = 0; d < DD; ++d) {
        uint w = *(const uint*)&X[d * NN + n];
        float gw = g_w[o * DD + d];
        a0 += gw * bf2f_lo(w);
        a1 += gw * bf2f_hi(w);
    }
    uint pack = (uint)f2bf_bits(a0) | ((uint)f2bf_bits(a1) << 16);
    *(uint*)&G_bf[idx] = pack;
}

// ---------- K3: flash attention, bf16 MFMA, fixed per-row softmax shift, split-K ----------
// m_n = rnorm[n]*mxnorm[b] >= row max (Cauchy-Schwarz) -> no max tracking, no rescale.
// l folded into PV via G row 60 == 1.0. 8 waves/block, QT=128 query rows.
// Double-buffered K/G LDS -> ONE barrier per tile; P-pass interleaved with PV
// (wave-internal LDS ops are in-order -> no barrier needed for P).
// __launch_bounds__(512,4): 128-VGPR budget ((512,8) caused spills, round 7).
template <int NS>
__global__ __launch_bounds__(512, 4) void k_attn(const ushort* __restrict__ xf_t,
                                                 const ushort* __restrict__ G_bf,
                                                 const float* __restrict__ rnorm,
                                                 const uint* __restrict__ mxbits,
                                                 float* __restrict__ Y,        // NS==1
                                                 ushort* __restrict__ O_bf) {  // NS>1: (s,b,64,N) bf16
    __shared__ char K_lds[2][KT * 128];
    __shared__ char G_lds[2][DP * 128];
    __shared__ char P_lds[NWAVE][16 * 128];

    int p = blockIdx.x;
    int s, b, q0;
    if (NS == NSPLIT) {
        // XCD-aware: xcd = p&7; each XCD pair-half owns one batch (4MB = one L2)
        int xcd = p & 7, slot = p >> 3;                // slot in [0,128)
        b = xcd >> 1;
        s = (xcd & 1) * 4 + (slot >> 5);
        q0 = (slot & 31) * QT;
    } else {
        s = 0;
        b = p >> 5;
        q0 = (p & 31) * QT;
    }
    int tid = threadIdx.x;
    int lane = tid & 63, wv = tid >> 6;
    int r = lane & 15, g = lane >> 4;

    const ushort* Xt = xf_t + (size_t)b * NN * DP;
    const ushort* Gb = G_bf + (size_t)b * DD * NN;

    int qrow = q0 + wv * 16 + r;
    s8v qa[2];
    qa[0] = *(const s8v*)&Xt[(size_t)qrow * DP + g * 8];
    qa[1] = *(const s8v*)&Xt[(size_t)qrow * DP + 32 + g * 8];

    // fixed per-row shift, rows 4g+0..3 of this lane
    float mx = __uint_as_float(mxbits[b]);
    float nm[4];
    #pragma unroll
    for (int reg = 0; reg < 4; ++reg)
        nm[reg] = -rnorm[b * NN + q0 + wv * 16 + 4 * g + reg] * mx * L2E;

    f4v of[4];
    #pragma unroll
    for (int i = 0; i < 4; ++i) of[i] = (f4v){0.f, 0.f, 0.f, 0.f};

    // staging: 512 threads x one 16B unit each per buffer; row = tid>>3, j = tid&7
    const int kr0 = tid >> 3, kj0 = tid & 7;
    const int kw0 = (kr0 * 128 + kj0 * 16) ^ ((kr0 & 7) << 4);
    const s8v ones8 = {(short)0x3F80, (short)0x3F80, (short)0x3F80, (short)0x3F80,
                       (short)0x3F80, (short)0x3F80, (short)0x3F80, (short)0x3F80};
    const s8v zero8 = {0, 0, 0, 0, 0, 0, 0, 0};
    s8v kp0, gp0;

    auto stage_regs = [&](int t) {
        int n0 = t * KT;
        kp0 = *(const s8v*)&Xt[(size_t)(n0 + kr0) * DP + kj0 * 8];
        gp0 = (kr0 < DD) ? *(const s8v*)&Gb[(size_t)kr0 * NN + n0 + kj0 * 8]
                         : (kr0 == DD ? ones8 : zero8);
    };
    auto lds_write = [&](int bu) {
        *(s8v*)(K_lds[bu] + kw0) = kp0;
        *(s8v*)(G_lds[bu] + kw0) = gp0;
    };

    const int t0 = s * (NTILES / NS);
    const int tend = t0 + NTILES / NS;
    char* Pw = P_lds[wv];

    stage_regs(t0);
    lds_write(0);
    __syncthreads();

    #pragma unroll 1
    for (int t = t0; t < tend; ++t) {
        const int cur = (t - t0) & 1;
        bool more = (t + 1 < tend);
        if (more) stage_regs(t + 1);          // global loads in flight during compute
        const char* Kc = K_lds[cur];
        const char* Gc = G_lds[cur];

        // ---- S = Q.K^T ----
        f4v sf[4];
        #pragma unroll
        for (int i = 0; i < 4; ++i) sf[i] = (f4v){0.f, 0.f, 0.f, 0.f};
        __builtin_amdgcn_s_setprio(1);
        #pragma unroll
        for (int kt2 = 0; kt2 < 4; ++kt2)
            #pragma unroll
            for (int kb = 0; kb < 2; ++kb) {
                int off = (((kt2 * 16 + r) * 128) + kb * 64 + g * 16) ^ ((r & 7) << 4);
                s8v bf = *(const s8v*)(Kc + off);
                sf[kt2] = __builtin_amdgcn_mfma_f32_16x16x32_bf16(qa[kb], bf, sf[kt2], 0, 0, 0);
            }
        __builtin_amdgcn_s_setprio(0);

        // ---- P for keys 0..31 (kt2 = 0,1) ----
        #pragma unroll
        for (int kt2 = 0; kt2 < 2; ++kt2)
            #pragma unroll
            for (int reg = 0; reg < 4; ++reg) {
                float pv = __builtin_exp2f(fmaf(sf[kt2][reg], L2E, nm[reg]));
                int row = 4 * g + reg;
                int boff = ((row * 128) + kt2 * 32 + 2 * r) ^ ((row & 7) << 4);
                *(ushort*)(Pw + boff) = f2bf_bits(pv);
            }
        // ---- PV kb=0 (wave-internal LDS is in-order; overlaps next P block) ----
        {
            int poff = ((r * 128) + g * 16) ^ ((r & 7) << 4);
            s8v pa = *(const s8v*)(Pw + poff);
            __builtin_amdgcn_s_setprio(1);
            #pragma unroll
            for (int ot = 0; ot < 4; ++ot) {
                int goff = (((ot * 16 + r) * 128) + g * 16) ^ ((r & 7) << 4);
                s8v gf = *(const s8v*)(Gc + goff);
                of[ot] = __builtin_amdgcn_mfma_f32_16x16x32_bf16(pa, gf, of[ot], 0, 0, 0);
            }
            __builtin_amdgcn_s_setprio(0);
        }
        // ---- P for keys 32..63 (kt2 = 2,3) ----
        #pragma unroll
        for (int kt2 = 2; kt2 < 4; ++kt2)
            #pragma unroll
            for (int reg = 0; reg < 4; ++reg) {
                float pv = __builtin_exp2f(fmaf(sf[kt2][reg], L2E, nm[reg]));
                int row = 4 * g + reg;
                int boff = ((row * 128) + kt2 * 32 + 2 * r) ^ ((row & 7) << 4);
                *(ushort*)(Pw + boff) = f2bf_bits(pv);
            }
        // ---- PV kb=1 ----
        {
            int poff = ((r * 128) + 64 + g * 16) ^ ((r & 7) << 4);
            s8v pa = *(const s8v*)(Pw + poff);
            __builtin_amdgcn_s_setprio(1);
            #pragma unroll
            for (int ot = 0; ot < 4; ++ot) {
                int goff = (((ot * 16 + r) * 128) + 64 + g * 16) ^ ((r & 7) << 4);
                s8v gf = *(const s8v*)(Gc + goff);
                of[ot] = __builtin_amdgcn_mfma_f32_16x16x32_bf16(pa, gf, of[ot], 0, 0, 0);
            }
            __builtin_amdgcn_s_setprio(0);
        }

        if (more) lds_write(cur ^ 1);         // write-late into the other buffer
        __syncthreads();                      // single barrier per tile
    }

    int qb = q0 + wv * 16 + 4 * g;
    if (NS == 1) {
        float linv[4];
        #pragma unroll
        for (int reg = 0; reg < 4; ++reg)
            linv[reg] = 1.0f / __shfl(of[3][reg], 12, 16);   // o=60 column holds l
        #pragma unroll
        for (int ot = 0; ot < 4; ++ot) {
            int o = ot * 16 + r;
            if (o < DD) {
                f4v v;
                #pragma unroll
                for (int reg = 0; reg < 4; ++reg) v[reg] = of[ot][reg] * linv[reg];
                *(f4v*)&Y[((size_t)(b * DD + o)) * NN + qb] = v;
            }
        }
    } else {
        ushort* Ob = O_bf + ((size_t)(s * BB + b) * DP) * NN;
        #pragma unroll
        for (int ot = 0; ot < 4; ++ot) {
            int o = ot * 16 + r;
            u4v v = {f2bf_bits(of[ot][0]), f2bf_bits(of[ot][1]),
                     f2bf_bits(of[ot][2]), f2bf_bits(of[ot][3])};
            *(u4v*)&Ob[(size_t)o * NN + qb] = v;                 // coalesced 32B per r-group
        }
    }
}

// ---------- K3b: combine split partials (shared m -> plain sums) -> Y (B,D,N), vec2 ----------
__global__ __launch_bounds__(256) void k_combine(const ushort* __restrict__ O_bf,
                                                 float* __restrict__ Y) {
    int u = blockIdx.x * 256 + threadIdx.x;            // over elems/2
    int idx = u * 2;
    int n = idx & (NN - 1);
    int o = (idx >> 12) % DD;
    int b = idx / (DD * NN);
    float a0 = 0.f, a1 = 0.f, L0 = 0.f, L1 = 0.f;
    #pragma unroll
    for (int s = 0; s < NSPLIT; ++s) {
        const ushort* Ob = O_bf + ((size_t)(s * BB + b) * DP) * NN + n;
        uint ov = *(const uint*)&Ob[(size_t)o * NN];
        uint lv = *(const uint*)&Ob[(size_t)DD * NN];
        a0 += bf2f_lo(ov); a1 += bf2f_hi(ov);
        L0 += bf2f_lo(lv); L1 += bf2f_hi(lv);
    }
    f2v y = {a0 / L0, a1 / L1};
    *(f2v*)&Y[idx] = y;
}

// ---------- K4: out = pixel_shuffle(w_w.Y + w_b) + x, pixel-major, vec2 over w ----------
__global__ __launch_bounds__(256) void k_out(const float* __restrict__ Y,
                                             const float* __restrict__ w_w,
                                             const float* __restrict__ w_b,
                                             const float* __restrict__ x,
                                             float* __restrict__ out) {
    __shared__ float ww[DD * DD];
    __shared__ float wb[DD];
    for (int i = threadIdx.x; i < DD * DD; i += 256) ww[i] = w_w[i];
    if (threadIdx.x < DD) wb[threadIdx.x] = w_b[threadIdx.x];
    __syncthreads();
    int u = blockIdx.x * 256 + threadIdx.x;            // over B*TC*H*(W/2)
    int w2 = u & 63;
    int h = (u >> 6) & 127;
    int rest = u >> 13;
    int c1 = rest % TC;
    int b = rest / TC;
    int o0 = c1 * 4 + (h & 1) * 2;                     // wave-uniform
    int n = ((h >> 1) << 6) + w2;
    const float* Yb = Y + (size_t)b * DD * NN + n;
    float a0 = wb[o0], a1 = wb[o0 + 1];
    #pragma unroll
    for (int d = 0; d < DD; ++d) {
        float y = Yb[(size_t)d * NN];
        a0 += ww[o0 * DD + d] * y;
        a1 += ww[(o0 + 1) * DD + d] * y;
    }
    size_t xi = ((size_t)(b * TC + c1) * HH + h) * HH + 2 * w2;
    f2v xv = *(const f2v*)&x[xi];
    f2v res = {a0 + xv[0], a1 + xv[1]};
    *(f2v*)&out[xi] = res;
}

extern "C" void kernel_launch(void* const* d_in, const int* in_sizes, int n_in,
                              void* d_out, int out_size, void* d_ws, size_t ws_size,
                              hipStream_t stream) {
    const float* x   = (const float*)d_in[0];
    const float* g_w = (const float*)d_in[1];
    const float* g_b = (const float*)d_in[2];
    const float* w_w = (const float*)d_in[3];
    const float* w_b = (const float*)d_in[4];
    float* out = (float*)d_out;

    char* ws = (char*)d_ws;
    ushort* xf_bf  = (ushort*)ws;                      // 1,966,080 B
    ushort* xf_t   = (ushort*)(ws + 1966080);          // 2,097,152 B
    ushort* G_bf   = (ushort*)(ws + 4063232);          // 1,966,080 B
    float*  rnorm  = (float*)(ws + 6029312);           // 65,536 B
    uint*   mxbits = (uint*)(ws + 6094848);            // 256 B (16 used)
    ushort* O_bf   = (ushort*)(ws + 6095104);          // 16,777,216 B -> end 22,872,320
    const size_t SPLIT_NEED = 22872320;

    hipMemsetAsync(mxbits, 0, BB * sizeof(uint), stream);
    k_prep<<<BB * NN / 64, 64, 0, stream>>>(x, xf_bf, xf_t, rnorm, mxbits);
    k_gproj<<<1920, 256, 0, stream>>>(xf_bf, g_w, g_b, G_bf);

    float* Y;
    if (ws_size >= SPLIT_NEED) {
        k_attn<NSPLIT><<<NSPLIT * BB * (NN / QT), 512, 0, stream>>>(
            xf_t, G_bf, rnorm, mxbits, nullptr, O_bf);
        Y = (float*)ws;                                // alias xf_bf+xf_t (dead after attn)
        k_combine<<<1920, 256, 0, stream>>>(O_bf, Y);
    } else {
        Y = (float*)(ws + 6095104);
        k_attn<1><<<BB * (NN / QT), 512, 0, stream>>>(
            xf_t, G_bf, rnorm, mxbits, Y, nullptr);
    }
    k_out<<<1920, 256, 0, stream>>>(Y, w_w, w_b, x, out);
}